// Round 8
// baseline (207.115 us; speedup 1.0000x reference)
//
#include <hip/hip_runtime.h>

#define BATCH 8
#define NNODE 10000
#define NEDGE 320000
#define HD    128
#define NROW  (BATCH * NNODE)       // 80000 rows
#define NEDG_TOT (BATCH * NEDGE)    // 2.56M edges
#define LDW 136                     // padded LDS row stride (bf16)
#define KB  64                      // hist/scatter blocks per batch
#define CEB (NEDGE / KB)            // 5000 edges per block
#define G   64                      // rows per coarse bucket
#define NBUCK 157                   // ceil(NNODE/G)
#define NBP 160                     // padded bucket stride
#define NBT (BATCH * NBP)           // 1280
#define EBUF 2560                   // bucket edge capacity (mean 2048, std ~45)

typedef __attribute__((ext_vector_type(8))) short short8;
typedef __attribute__((ext_vector_type(4))) float f32x4;

__device__ __forceinline__ short f2bf(float f) {
    unsigned u = __float_as_uint(f);
    unsigned r = u + 0x7FFFu + ((u >> 16) & 1u);   // RNE
    return (short)(r >> 16);
}
__device__ __forceinline__ float bflo(unsigned y) { return __uint_as_float(y << 16); }
__device__ __forceinline__ float bfhi(unsigned y) { return __uint_as_float(y & 0xffff0000u); }

// ---------- pass 1: per-block LDS histograms: fine degree + coarse count ----------
__global__ __launch_bounds__(256) void k_hist(const float* __restrict__ adj,
                                              const int* __restrict__ src,
                                              float* __restrict__ bdeg,
                                              int* __restrict__ cc) {
    __shared__ float sdeg[NNODE];   // 40 KB
    __shared__ int   scc[NBP];
    int t = threadIdx.x, blk = blockIdx.x;
    for (int i = t; i < NNODE; i += 256) sdeg[i] = 0.f;
    if (t < NBP) scc[t] = 0;
    __syncthreads();
    int b = blk >> 6, kb = blk & (KB - 1);
    long e0 = (long)b * NEDGE + (long)kb * CEB;
    for (int i = t; i < CEB; i += 256) {
        long e = e0 + i;
        int s = src[e];
        atomicAdd(&sdeg[s], adj[e]);
        atomicAdd(&scc[s >> 6], 1);
    }
    __syncthreads();
    float* bd = bdeg + (long)blk * NNODE;
    for (int i = t; i < NNODE; i += 256) bd[i] = sdeg[i];
    if (t < NBP) cc[blk * NBP + t] = scc[t];
}

// ---------- per-row norm from per-block degree partials ----------
__global__ __launch_bounds__(256) void k_norm(const float* __restrict__ bdeg,
                                              float* __restrict__ norm) {
    int r = blockIdx.x * 256 + threadIdx.x;
    if (r >= NROW) return;
    int b = r / NNODE, n = r % NNODE;
    const float* bd = bdeg + (long)b * KB * NNODE + n;
    float ds = 0.f;
    #pragma unroll
    for (int k = 0; k < KB; ++k) ds += bd[(long)k * NNODE];
    norm[r] = rsqrtf(ds + 1e-6f);
}

// ---------- coarse chain, fully merged: totals + scan + per-block bases ----------
__global__ __launch_bounds__(256) void k_coarse(int* __restrict__ cc,
                                                int* __restrict__ tot_c,
                                                int* __restrict__ cbase) {
    __shared__ int part[256];
    int t = threadIdx.x;
    int tot[5], loc[5]; int run = 0;
    #pragma unroll
    for (int j = 0; j < 5; ++j) {
        int gi = t * 5 + j, b = gi / NBP, bk = gi % NBP;
        int s = 0;
        for (int k = 0; k < KB; ++k) s += cc[(b * KB + k) * NBP + bk];
        tot[j] = s; loc[j] = run; run += s;
    }
    part[t] = run; __syncthreads();
    for (int off = 1; off < 256; off <<= 1) {
        int a = part[t]; int add = (t >= off) ? part[t - off] : 0;
        __syncthreads();
        part[t] = a + add;
        __syncthreads();
    }
    int excl = (t == 0) ? 0 : part[t - 1];
    #pragma unroll
    for (int j = 0; j < 5; ++j) {
        int gi = t * 5 + j, b = gi / NBP, bk = gi % NBP;
        tot_c[gi] = tot[j];
        cbase[gi] = excl + loc[j];
        int run2 = excl + loc[j];
        for (int k = 0; k < KB; ++k) {
            int idx = (b * KB + k) * NBP + bk;
            int c = cc[idx];
            cc[idx] = run2;
            run2 += c;
        }
    }
}

// ---------- coarse scatter (64-row buckets), fold norm[dst] into value ----------
__global__ __launch_bounds__(256) void k_scatA(const float* __restrict__ adj,
                                               const int* __restrict__ src,
                                               const int* __restrict__ dst,
                                               const float* __restrict__ norm,
                                               const int* __restrict__ cbases,
                                               int2* __restrict__ epairA) {
    __shared__ int cur[NBP];
    int t = threadIdx.x, blk = blockIdx.x;
    if (t < NBP) cur[t] = cbases[blk * NBP + t];
    __syncthreads();
    int b = blk >> 6, kb = blk & (KB - 1);
    const float* nb = norm + b * NNODE;
    long e0 = (long)b * NEDGE + (long)kb * CEB;
    for (int i = t; i < CEB; i += 256) {
        long e = e0 + i;
        int s = src[e], d = dst[e];
        float v = adj[e] * nb[d];
        int p = atomicAdd(&cur[s >> 6], 1);
        epairA[p] = make_int2((s << 16) | d, __float_as_int(v));
    }
}

// ---------- weights -> bf16 transposed ----------
__global__ __launch_bounds__(256) void k_wcvt(const float* __restrict__ th,
                                              const float* __restrict__ Wt,
                                              const float* __restrict__ Wh,
                                              short* __restrict__ wbf) {
    int i = blockIdx.x * 256 + threadIdx.x;
    int w = i >> 14, idx = i & 16383;
    int n = idx >> 7, k = idx & 127;
    const float* W = (w == 0) ? th : ((w == 1) ? Wt : Wh);
    wbf[i] = f2bf(W[k * HD + n]);
}

// ---------- Y = bf16( x@theta )  (unnormalized; norms folded elsewhere) ----------
__global__ __launch_bounds__(256) void k_theta(const float* __restrict__ x,
                                               const short* __restrict__ thT,
                                               short* __restrict__ Y) {
    __shared__ short lb[HD * LDW];
    int tx = threadIdx.x;
    for (int i = tx; i < HD * 16; i += 256) {
        int n = i >> 4, kc = (i & 15) << 3;
        *(float4*)(&lb[n * LDW + kc]) = *(const float4*)(&thT[n * HD + kc]);
    }
    __syncthreads();

    int wv = tx >> 6, l = tx & 63;
    long row0 = (long)blockIdx.x * 64 + wv * 16;
    int mrow = l & 15, kg = l >> 4;
    const float* xp = x + (row0 + mrow) * HD + kg * 8;

    f32x4 acc[8];
    #pragma unroll
    for (int f = 0; f < 8; ++f) acc[f] = (f32x4){0.f, 0.f, 0.f, 0.f};

    #pragma unroll
    for (int c = 0; c < 4; ++c) {
        float4 a0 = *(const float4*)(xp + c * 32);
        float4 a1 = *(const float4*)(xp + c * 32 + 4);
        short8 a;
        a[0]=f2bf(a0.x); a[1]=f2bf(a0.y); a[2]=f2bf(a0.z); a[3]=f2bf(a0.w);
        a[4]=f2bf(a1.x); a[5]=f2bf(a1.y); a[6]=f2bf(a1.z); a[7]=f2bf(a1.w);
        #pragma unroll
        for (int f = 0; f < 8; ++f) {
            short8 b = *(short8*)(&lb[(16 * f + mrow) * LDW + c * 32 + kg * 8]);
            acc[f] = __builtin_amdgcn_mfma_f32_16x16x32_bf16(a, b, acc[f], 0, 0, 0);
        }
    }
    #pragma unroll
    for (int f = 0; f < 8; ++f)
        #pragma unroll
        for (int r = 0; r < 4; ++r)
            Y[(row0 + kg * 4 + r) * HD + 16 * f + mrow] = f2bf(acc[f][r]);
}

// ---------- bucket kernel: in-LDS row sort + per-row register gather ----------
__global__ __launch_bounds__(256) void k_bucket(const int* __restrict__ cbase,
                                                const int* __restrict__ tot_c,
                                                const int2* __restrict__ epairA,
                                                const short* __restrict__ Y,
                                                const float* __restrict__ norm,
                                                float* __restrict__ out) {
    __shared__ int  rpt[G + 1];
    __shared__ int  rcnt[G];
    __shared__ int  rcur[G];
    __shared__ int2 ebuf[EBUF];     // 20 KB
    int t = threadIdx.x;
    int batch = blockIdx.x & 7, bk = blockIdx.x >> 3;   // batch -> XCD
    if (t < G) rcnt[t] = 0;
    __syncthreads();
    int gi = batch * NBP + bk;
    int p0 = cbase[gi], n = tot_c[gi];

    // phase 1: cache edges in registers (lane-parallel, coalesced) + count rows
    int2 ecache[10];
    #pragma unroll
    for (int j = 0; j < 10; ++j) {
        int i = j * 256 + t;
        if (i < n) {
            int2 e = epairA[p0 + i];
            ecache[j] = e;
            atomicAdd(&rcnt[(e.x >> 16) & (G - 1)], 1);
        }
    }
    __syncthreads();

    // phase 2: 64-wide shfl scan (wave 0) -> local rowptr + cursors
    if (t < G) {
        int v = rcnt[t];
        int inc = v;
        #pragma unroll
        for (int off = 1; off < G; off <<= 1) {
            int u = __shfl_up(inc, off, G);
            if (t >= off) inc += u;
        }
        rpt[t + 1] = inc;
        rcur[t] = inc - v;
        if (t == 0) rpt[0] = 0;
    }
    __syncthreads();

    // phase 3: place edges row-sorted into LDS
    #pragma unroll
    for (int j = 0; j < 10; ++j) {
        int i = j * 256 + t;
        if (i < n) {
            int2 e = ecache[j];
            int rl = (e.x >> 16) & (G - 1);
            int p = atomicAdd(&rcur[rl], 1);
            ebuf[p] = make_int2(e.x & 0xffff, e.y);
        }
    }
    __syncthreads();

    // phase 4: each wave consumes rows rl = wv, wv+4, ... (broadcast LDS edge reads)
    int wv = t >> 6, lane = t & 63;
    const short* Yb = Y + (long)batch * NNODE * HD + 2 * lane;
    for (int rl = wv; rl < G; rl += 4) {
        int node = bk * G + rl;
        if (node >= NNODE) break;                   // last bucket only
        int s = rpt[rl], eN = rpt[rl + 1];
        float ax = 0.f, ay = 0.f;
        int i = s;
        for (; i + 4 <= eN; i += 4) {
            int2 e0 = ebuf[i], e1 = ebuf[i + 1], e2 = ebuf[i + 2], e3 = ebuf[i + 3];
            unsigned y0 = *(const unsigned*)(Yb + (long)e0.x * HD);
            unsigned y1 = *(const unsigned*)(Yb + (long)e1.x * HD);
            unsigned y2 = *(const unsigned*)(Yb + (long)e2.x * HD);
            unsigned y3 = *(const unsigned*)(Yb + (long)e3.x * HD);
            float v0 = __int_as_float(e0.y), v1 = __int_as_float(e1.y);
            float v2 = __int_as_float(e2.y), v3 = __int_as_float(e3.y);
            ax += v0 * bflo(y0); ay += v0 * bfhi(y0);
            ax += v1 * bflo(y1); ay += v1 * bfhi(y1);
            ax += v2 * bflo(y2); ay += v2 * bfhi(y2);
            ax += v3 * bflo(y3); ay += v3 * bfhi(y3);
        }
        for (; i < eN; ++i) {
            int2 e = ebuf[i];
            unsigned y = *(const unsigned*)(Yb + (long)e.x * HD);
            float v = __int_as_float(e.y);
            ax += v * bflo(y); ay += v * bfhi(y);
        }
        long r = (long)batch * NNODE + node;
        float nr = norm[r];
        ((float2*)(out + r * HD))[lane] = make_float2(ax * nr, ay * nr);
    }
}

// ---------- out = g * z + (1-g) * (x@Wh), g = sigmoid(x@Wt+b); z read from out ----------
__global__ __launch_bounds__(256) void k_final(const float* __restrict__ x,
                                               const short* __restrict__ WtT,
                                               const short* __restrict__ WhT,
                                               const float* __restrict__ bt,
                                               float* __restrict__ out) {
    __shared__ short lb[2 * HD * LDW];
    int tx = threadIdx.x;
    for (int i = tx; i < HD * 16; i += 256) {
        int n = i >> 4, kc = (i & 15) << 3;
        *(float4*)(&lb[n * LDW + kc])            = *(const float4*)(&WtT[n * HD + kc]);
        *(float4*)(&lb[HD * LDW + n * LDW + kc]) = *(const float4*)(&WhT[n * HD + kc]);
    }
    __syncthreads();

    int wv = tx >> 6, l = tx & 63;
    long row0 = (long)blockIdx.x * 64 + wv * 16;
    int mrow = l & 15, kg = l >> 4;
    const float* xp = x + (row0 + mrow) * HD + kg * 8;

    f32x4 at[8], ah[8];
    #pragma unroll
    for (int f = 0; f < 8; ++f) { at[f] = (f32x4){0.f,0.f,0.f,0.f}; ah[f] = (f32x4){0.f,0.f,0.f,0.f}; }

    #pragma unroll
    for (int c = 0; c < 4; ++c) {
        float4 a0 = *(const float4*)(xp + c * 32);
        float4 a1 = *(const float4*)(xp + c * 32 + 4);
        short8 a;
        a[0]=f2bf(a0.x); a[1]=f2bf(a0.y); a[2]=f2bf(a0.z); a[3]=f2bf(a0.w);
        a[4]=f2bf(a1.x); a[5]=f2bf(a1.y); a[6]=f2bf(a1.z); a[7]=f2bf(a1.w);
        #pragma unroll
        for (int f = 0; f < 8; ++f) {
            short8 b0 = *(short8*)(&lb[(16 * f + mrow) * LDW + c * 32 + kg * 8]);
            short8 b1 = *(short8*)(&lb[HD * LDW + (16 * f + mrow) * LDW + c * 32 + kg * 8]);
            at[f] = __builtin_amdgcn_mfma_f32_16x16x32_bf16(a, b0, at[f], 0, 0, 0);
            ah[f] = __builtin_amdgcn_mfma_f32_16x16x32_bf16(a, b1, ah[f], 0, 0, 0);
        }
    }
    #pragma unroll
    for (int f = 0; f < 8; ++f) {
        float bb = bt[16 * f + mrow];
        #pragma unroll
        for (int r = 0; r < 4; ++r) {
            long row = row0 + kg * 4 + r;
            long idx = row * HD + 16 * f + mrow;
            float z = out[idx];
            float g = 1.f / (1.f + __expf(-(at[f][r] + bb)));
            out[idx] = g * z + (1.f - g) * ah[f][r];
        }
    }
}

extern "C" void kernel_launch(void* const* d_in, const int* in_sizes, int n_in,
                              void* d_out, int out_size, void* d_ws, size_t ws_size,
                              hipStream_t stream) {
    const float* x     = (const float*)d_in[0];
    const float* adj   = (const float*)d_in[1];
    const int*   src   = (const int*)d_in[2];
    const int*   dst   = (const int*)d_in[3];
    const float* Wt    = (const float*)d_in[4];
    const float* bt    = (const float*)d_in[5];
    const float* Wh    = (const float*)d_in[6];
    const float* theta = (const float*)d_in[7];
    float* out = (float*)d_out;

    // workspace: ~41.7 MB (< 42.84 MB proven in R7)
    char* p = (char*)d_ws;
    float* norm   = (float*)p;  p += (size_t)NROW * 4;            // 320,000
    int*   tot_c  = (int*)p;    p += (size_t)NBT * 4;             // 5,120
    int*   cbase  = (int*)p;    p += (size_t)NBT * 4;             // 5,120
    int*   cc     = (int*)p;    p += (size_t)BATCH * KB * NBP * 4;// 327,680
    short* wbf    = (short*)p;  p += 3 * 16384 * 2;               // 98,304
    // RegionA (20.48 MB): bdeg (hist->norm) then Y (theta->bucket)
    float* bdeg   = (float*)p;
    short* Y      = (short*)p;  p += (size_t)NROW * HD * 2;       // 20,480,000
    int2*  epairA = (int2*)p;   p += (size_t)(NEDG_TOT + 64) * 8; // 20,480,512

    k_hist  <<<BATCH * KB, 256, 0, stream>>>(adj, src, bdeg, cc);
    k_norm  <<<(NROW + 255) / 256, 256, 0, stream>>>(bdeg, norm);
    k_coarse<<<1, 256, 0, stream>>>(cc, tot_c, cbase);
    k_scatA <<<BATCH * KB, 256, 0, stream>>>(adj, src, dst, norm, cc, epairA);
    k_wcvt  <<<3 * 16384 / 256, 256, 0, stream>>>(theta, Wt, Wh, wbf);
    k_theta <<<NROW / 64, 256, 0, stream>>>(x, wbf, Y);          // Y overwrites bdeg (dead)
    k_bucket<<<BATCH * NBUCK, 256, 0, stream>>>(cbase, tot_c, epairA, Y, norm, out);
    k_final <<<NROW / 64, 256, 0, stream>>>(x, wbf + 16384, wbf + 2 * 16384, bt, out);
}